// Round 4
// baseline (4946.178 us; speedup 1.0000x reference)
//
#include <hip/hip_runtime.h>
#include <stdint.h>

// ============================================================================
// 2-layer GRU decoder, B=128, T=512, H=256, heads 128/64/64 (concat=256).
// Persistent latency design + SPLIT-F16 precision (effectively fp32 matmuls):
//   A*W ~= Ah*Wh + (Al_s*Wh + Ah*Wl_s)/2048, lo-parts pre-scaled by 2^11.
// Sync: FLAGLESS tagged exchange. Each pub entry is an atomic 8B
//   {payload, step-tag} store (sc0 sc1 -> LLC). Readers poll their own data
//   chunk until all 16 tags match the step counter -> one LLC round trip per
//   exchange instead of drain+flag-store+flag-poll+data-load. Double-buffered
//   by step parity (provably race-free given the all-16-block dependency per
//   exchange). init2 zeroes tag words; replay-stale tags carry bit-identical
//   payloads (deterministic kernel), so graph replays are safe.
// ============================================================================

typedef __attribute__((ext_vector_type(8))) _Float16 half8;
typedef __attribute__((ext_vector_type(4))) float f32x4;
typedef __attribute__((ext_vector_type(4))) unsigned int u32x4;
typedef __attribute__((ext_vector_type(2))) unsigned int u32x2;

// blob fragment-unit (16B) section bases
#define HIU(b,p,g)  ((unsigned)((b)*24576u + ((p)*3u+(g))*512u))
#define LOU(b,p,g)  ((unsigned)(122880u + (b)*24576u + ((p)*3u+(g))*512u))
#define HEADU(p)    ((unsigned)(245760u + (p)*512u))
#define NUNITS      253952u

// workspace offsets (bytes)
// pub: 4 buffers (h0n/h1n x parity) of 32768 entries * 8B = 262144B each
#define PUB_OFF   0u
#define BP_OFF    1048576u
#define BLOB_OFF  1051648u
#define WS_NEEDED (BLOB_OFF + NUNITS*16u)   // ~5.11 MB (same as prior round)

// LDS offsets (bytes)
#define HA_HI 0u
#define HA_LO 8192u
#define HB_HI 16384u
#define HB_LO 24576u
#define SCR   32768u        // 6 slots * 288 fp32 (17-stride pad) = 6912B
#define BIASO 39680u        // 256 floats
#define WLDS  40960u        // 4 waves * 2 sets * 8KB + head 8KB
#define LDS_TOTAL (40960u + 73728u)   // 114688 B

__device__ __forceinline__ uint16_t f2h_bits(float x) {
  _Float16 h = (_Float16)x;
  return __builtin_bit_cast(uint16_t, h);
}
__device__ __forceinline__ float sigmoidf_(float x) { return 1.f / (1.f + __expf(-x)); }

// coherent (LLC point-of-coherence) ops — empirically validated in round 3
__device__ __forceinline__ void st_cc_x2(uint32_t* p, u32x2 v) {
  asm volatile("global_store_dwordx2 %0, %1, off sc0 sc1" :: "v"(p), "v"(v) : "memory");
}

// ---------------------------------------------------------------------------
// init1: W' = Wih0 @ Wcat written DIRECTLY as split-f16 blob (b=0 sections);
//        b' = bih0 + Wih0 . bcat -> bp.
// ---------------------------------------------------------------------------
__global__ void gru_init1(const float* __restrict__ Wih0, const float* __restrict__ Wn,
                          const float* __restrict__ Wd, const float* __restrict__ Wg,
                          const float* __restrict__ bn, const float* __restrict__ bd,
                          const float* __restrict__ bg, const float* __restrict__ bih0,
                          uint16_t* __restrict__ BW, float* __restrict__ bp)
{
  const int i = blockIdx.x;   // 0..767  (gate-major row of W')
  const int j = threadIdx.x;  // 0..255  (column)
  float acc = 0.f;
  for (int k = 0; k < 256; ++k) {
    float w = Wih0[i*256 + k];
    float c = (k < 128) ? Wn[k*256 + j] : (k < 192) ? Wd[(k-128)*256 + j] : Wg[(k-192)*256 + j];
    acc += w * c;
  }
  // blob address: unit (p*3+g)*512 + kt*64 + (c4*16+r), element e
  const uint32_t g = (uint32_t)i >> 8, p = ((uint32_t)i & 255u) >> 4, r = (uint32_t)i & 15u;
  const uint32_t kt = (uint32_t)j >> 5, c4 = ((uint32_t)j >> 3) & 3u, e = (uint32_t)j & 7u;
  const uint32_t base = ((p*3u + g)*512u + kt*64u + c4*16u + r)*8u + e;
  _Float16 hi = (_Float16)acc;
  BW[base] = __builtin_bit_cast(uint16_t, hi);
  BW[122880u*8u + base] = f2h_bits((acc - (float)hi) * 2048.f);
  if (j == 0) {
    float bb = bih0[i];
    for (int k = 0; k < 256; ++k) {
      float bc = (k < 128) ? bn[k] : (k < 192) ? bd[k-128] : bg[k-192];
      bb += Wih0[i*256 + k] * bc;
    }
    bp[i] = bb;
  }
}

// ---------------------------------------------------------------------------
// init2: split-f16 blobs for b=1..4 + head; b=0-range threads zero pub tags.
// ---------------------------------------------------------------------------
__global__ void gru_init2(const float* __restrict__ Wih0, const float* __restrict__ Whh0,
                          const float* __restrict__ Wih1, const float* __restrict__ Whh1,
                          const float* __restrict__ Wn, const float* __restrict__ Wd,
                          const float* __restrict__ Wg,
                          uint32_t* __restrict__ pub, uint16_t* __restrict__ BW)
{
  const uint32_t u = blockIdx.x*256u + threadIdx.x;   // 0..253951
  const bool isB0 = (u < 24576u) || (u >= 122880u && u < 147456u);
  if (isB0) {
    // zero the 131072 pub tag words (kernel-boundary flush makes them visible)
    const uint32_t zi = (u < 24576u) ? u : (u - 122880u + 24576u);  // 0..49151
#pragma unroll
    for (uint32_t k = 0; k < 3; ++k) {
      const uint32_t w = zi + k*49152u;
      if (w < 131072u) pub[w*2u + 1u] = 0u;
    }
    return;
  }
  bool lo = false;
  const float* s;
  if (u < 245760u) {
    uint32_t v = u;
    if (v >= 122880u) { v -= 122880u; lo = true; }
    uint32_t b = v/24576u, rem = v%24576u;          // b in 1..4 here
    uint32_t p = rem/1536u, r2 = rem%1536u;
    uint32_t g = r2/512u,  r3 = r2%512u;
    uint32_t kt = r3>>6,   l = r3&63u;
    const float* W = (b==1)?Wih0:(b==2)?Whh0:(b==3)?Wih1:Whh1;
    s = W + (size_t)(g*256u + p*16u + (l&15u))*256u + kt*32u + (l>>4)*8u;
  } else {
    uint32_t rem = u - 245760u;
    uint32_t p = rem/512u, r3 = rem%512u;
    uint32_t kt = r3>>6,   l = r3&63u;
    uint32_t row = p*16u + (l&15u), k0 = kt*32u + (l>>4)*8u;
    s = (row < 128u) ? (Wn + (size_t)row*256u + k0)
      : (row < 192u) ? (Wd + (size_t)(row-128u)*256u + k0)
      :                (Wg + (size_t)(row-192u)*256u + k0);
  }
  u32x4 vv;
#pragma unroll
  for (int i = 0; i < 4; ++i) {
    float w0 = s[2*i], w1 = s[2*i+1];
    uint16_t b0, b1;
    if (!lo) { b0 = f2h_bits(w0); b1 = f2h_bits(w1); }
    else {
      float r0 = w0 - (float)((_Float16)w0);
      float r1 = w1 - (float)((_Float16)w1);
      b0 = f2h_bits(r0 * 2048.f); b1 = f2h_bits(r1 * 2048.f);
    }
    vv[i] = (uint32_t)b0 | ((uint32_t)b1 << 16);
  }
  *(u32x4*)(BW + (size_t)u * 8u) = vv;
}

// ---------------------------------------------------------------------------
// main persistent kernel: 128 blocks x 256 threads, 512 steps.
// ---------------------------------------------------------------------------
__launch_bounds__(256, 1)
__global__ void gru_main(const float* __restrict__ x0in,
                         const float* __restrict__ bih0, const float* __restrict__ bhh0,
                         const float* __restrict__ bih1, const float* __restrict__ bhh1,
                         const float* __restrict__ bn, const float* __restrict__ bd,
                         const float* __restrict__ bg, const float* __restrict__ bp,
                         const uint16_t* __restrict__ BW,
                         uint32_t* __restrict__ pub,
                         float* __restrict__ out)
{
  extern __shared__ char smem[];
  const int tid  = threadIdx.x;
  const int lane = tid & 63;
  const int wv   = tid >> 6;
  const int cl   = blockIdx.x & 7;
  const int p    = blockIdx.x >> 3;

  // ---- biases -> LDS: [0)b' [48)bih0 [96)bhh0 [144)bih1 [192)bhh1 [240)bhead
  if (tid < 48) {
    const int gi = (tid >> 4)*256 + p*16 + (tid & 15);
    float* bbw = (float*)(smem + BIASO);
    bbw[tid]       = bp[gi];
    bbw[48 + tid]  = bih0[gi];
    bbw[96 + tid]  = bhh0[gi];
    bbw[144 + tid] = bih1[gi];
    bbw[192 + tid] = bhh1[gi];
  }
  if (tid < 16) {
    const int jg = p*16 + tid;
    float v = (jg < 128) ? bn[jg] : (jg < 192) ? bd[jg-128] : bg[jg-192];
    ((float*)(smem + BIASO))[240 + tid] = v;
  }
  // ---- x0 -> HB hi/lo (split f16, XOR-swizzled)
  {
    const int row = tid >> 4, ch = tid & 15;
    const float* sp = x0in + (size_t)(cl*16 + row)*256 + ch*16;
    const uint32_t base = (uint32_t)(row*512 + ch*32);
    const uint32_t swz  = (uint32_t)((row & 7) << 4);
#pragma unroll
    for (int half = 0; half < 2; ++half) {
      u32x4 vh, vl;
#pragma unroll
      for (int i = 0; i < 4; ++i) {
        float w0 = sp[half*8 + 2*i], w1 = sp[half*8 + 2*i + 1];
        _Float16 h0 = (_Float16)w0, h1 = (_Float16)w1;
        _Float16 l0 = (_Float16)((w0 - (float)h0)*2048.f);
        _Float16 l1 = (_Float16)((w1 - (float)h1)*2048.f);
        vh[i] = (uint32_t)__builtin_bit_cast(uint16_t,h0) | ((uint32_t)__builtin_bit_cast(uint16_t,h1) << 16);
        vl[i] = (uint32_t)__builtin_bit_cast(uint16_t,l0) | ((uint32_t)__builtin_bit_cast(uint16_t,l1) << 16);
      }
      *(u32x4*)(smem + HB_HI + ((base + half*16) ^ swz)) = vh;
      *(u32x4*)(smem + HB_LO + ((base + half*16) ^ swz)) = vl;
    }
  }

  // ---- weight fragments -> registers (hi sets + phase-A lo sets)
  // P: w0:W'g0 w1:W'g1 w2:W'g2 w3:Whh0g2 | Q (w0,w1): Whh0g0/g1
  // R: w0:Wih1g0 w1:Wih1g1 w2:Wih1g2 w3:Whh1g1 | S: w2:Whh1g0 w3:Whh1g2
  half8 wPh[8], wPl[8], wQh[8], wQl[8], wRh[8], wSh[8];
  {
    unsigned uPh, uPl, uQh = 0, uQl = 0, uRh, uSh = 0;
    bool hasQ = (wv < 2), hasS = (wv >= 2);
    if (wv == 0)      { uPh=HIU(0,p,0); uPl=LOU(0,p,0); uQh=HIU(2,p,0); uQl=LOU(2,p,0); uRh=HIU(3,p,0); }
    else if (wv == 1) { uPh=HIU(0,p,1); uPl=LOU(0,p,1); uQh=HIU(2,p,1); uQl=LOU(2,p,1); uRh=HIU(3,p,1); }
    else if (wv == 2) { uPh=HIU(0,p,2); uPl=LOU(0,p,2); uRh=HIU(3,p,2); uSh=HIU(4,p,0); }
    else              { uPh=HIU(2,p,2); uPl=LOU(2,p,2); uRh=HIU(4,p,1); uSh=HIU(4,p,2); }
#pragma unroll
    for (int kt = 0; kt < 8; ++kt) {
      wPh[kt] = *(const half8*)(BW + (size_t)(uPh + kt*64 + lane)*8);
      wPl[kt] = *(const half8*)(BW + (size_t)(uPl + kt*64 + lane)*8);
      wRh[kt] = *(const half8*)(BW + (size_t)(uRh + kt*64 + lane)*8);
    }
    if (hasQ) {
#pragma unroll
      for (int kt = 0; kt < 8; ++kt) {
        wQh[kt] = *(const half8*)(BW + (size_t)(uQh + kt*64 + lane)*8);
        wQl[kt] = *(const half8*)(BW + (size_t)(uQl + kt*64 + lane)*8);
      }
    }
    if (hasS) {
#pragma unroll
      for (int kt = 0; kt < 8; ++kt)
        wSh[kt] = *(const half8*)(BW + (size_t)(uSh + kt*64 + lane)*8);
    }
  }
  // ---- phase-B lo sets + head weights -> LDS (per-wave regions)
  const uint32_t rloofs = WLDS + (uint32_t)wv*16384u;
  const uint32_t sloofs = rloofs + 8192u;
  {
    unsigned uRl, uSl = 0xFFFFFFFFu;
    if (wv == 0)      { uRl = LOU(3,p,0); }
    else if (wv == 1) { uRl = LOU(3,p,1); }
    else if (wv == 2) { uRl = LOU(3,p,2); uSl = LOU(4,p,0); }
    else              { uRl = LOU(4,p,1); uSl = LOU(4,p,2); }
#pragma unroll
    for (int kt = 0; kt < 8; ++kt)
      *(u32x4*)(smem + rloofs + (uint32_t)((kt*64 + lane)*16)) =
          *(const u32x4*)(BW + (size_t)(uRl + kt*64 + lane)*8);
    if (uSl != 0xFFFFFFFFu) {
#pragma unroll
      for (int kt = 0; kt < 8; ++kt)
        *(u32x4*)(smem + sloofs + (uint32_t)((kt*64 + lane)*16)) =
            *(const u32x4*)(BW + (size_t)(uSl + kt*64 + lane)*8);
    }
    if (wv == 3) {
      const unsigned uH = HEADU(p);
#pragma unroll
      for (int kt = 0; kt < 8; ++kt)
        *(u32x4*)(smem + WLDS + 65536u + (uint32_t)((kt*64 + lane)*16)) =
            *(const u32x4*)(BW + (size_t)(uH + kt*64 + lane)*8);
    }
  }
  __syncthreads();

  const int arow = lane & 15;
  const uint32_t abase = (uint32_t)(arow*512 + ((lane >> 4) << 4));
  const uint32_t aswz  = (uint32_t)((arow & 7) << 4);

  auto LDA = [&](half8* dst, uint32_t buf) {
#pragma unroll
    for (int kt = 0; kt < 8; ++kt)
      dst[kt] = *(const half8*)(smem + buf + ((abase + (uint32_t)(kt*64)) ^ aswz));
  };
  auto CH = [&](const half8* A, const half8* W, f32x4 acc) -> f32x4 {
#pragma unroll
    for (int kt = 0; kt < 8; ++kt)
      acc = __builtin_amdgcn_mfma_f32_16x16x32_f16(A[kt], W[kt], acc, 0, 0, 0);
    return acc;
  };
  auto CHL = [&](const half8* A, uint32_t wofs, f32x4 acc) -> f32x4 {
#pragma unroll
    for (int kt = 0; kt < 8; ++kt) {
      half8 w = *(const half8*)(smem + wofs + (uint32_t)((kt*64 + lane)*16));
      acc = __builtin_amdgcn_mfma_f32_16x16x32_f16(A[kt], w, acc, 0, 0, 0);
    }
    return acc;
  };
  auto CHG = [&](const half8* A, unsigned ubase, f32x4 acc) -> f32x4 {
#pragma unroll
    for (int kt = 0; kt < 8; ++kt) {
      half8 w = *(const half8*)(BW + (size_t)(ubase + kt*64 + lane)*8);
      acc = __builtin_amdgcn_mfma_f32_16x16x32_f16(A[kt], w, acc, 0, 0, 0);
    }
    return acc;
  };
  // C-tile scratch, 17-stride pad (conflict-spread): addr = slot*288 + row*17 + col
  auto SCW = [&](int slot, f32x4 a) {
    float* sc = (float*)(smem + SCR) + slot*288 + (lane >> 4)*68 + (lane & 15);
    sc[0] = a[0]; sc[17] = a[1]; sc[34] = a[2]; sc[51] = a[3];
  };
  // flagless tagged poll + LDS assemble
  auto passemble = [&](uint32_t dhib, uint32_t dlob, const uint32_t* buf, uint32_t tag) {
    const int row = tid >> 4, ch = tid & 15;
    const uint32_t* bp2 = buf + (uint32_t)(cl*4096 + row*256 + ch*16)*2u;
    u32x4 q0,q1,q2,q3,q4,q5,q6,q7;
    uint32_t gd = 0;
    for (;;) {
      asm volatile(
        "global_load_dwordx4 %0, %8, off sc0 sc1\n\t"
        "global_load_dwordx4 %1, %8, off offset:16 sc0 sc1\n\t"
        "global_load_dwordx4 %2, %8, off offset:32 sc0 sc1\n\t"
        "global_load_dwordx4 %3, %8, off offset:48 sc0 sc1\n\t"
        "global_load_dwordx4 %4, %8, off offset:64 sc0 sc1\n\t"
        "global_load_dwordx4 %5, %8, off offset:80 sc0 sc1\n\t"
        "global_load_dwordx4 %6, %8, off offset:96 sc0 sc1\n\t"
        "global_load_dwordx4 %7, %8, off offset:112 sc0 sc1\n\t"
        "s_waitcnt vmcnt(0)"
        : "=&v"(q0),"=&v"(q1),"=&v"(q2),"=&v"(q3),
          "=&v"(q4),"=&v"(q5),"=&v"(q6),"=&v"(q7)
        : "v"(bp2) : "memory");
      bool ok = (q0[1]==tag)&(q0[3]==tag)&(q1[1]==tag)&(q1[3]==tag)
              & (q2[1]==tag)&(q2[3]==tag)&(q3[1]==tag)&(q3[3]==tag)
              & (q4[1]==tag)&(q4[3]==tag)&(q5[1]==tag)&(q5[3]==tag)
              & (q6[1]==tag)&(q6[3]==tag)&(q7[1]==tag)&(q7[3]==tag);
      if (ok || gd >= 32768u) break;
      // backoff-gate: cheap 1x dwordx4 probe until last pair fresh
      u32x4 g7;
      do {
        __builtin_amdgcn_s_sleep(1);
        asm volatile("global_load_dwordx4 %0, %1, off offset:112 sc0 sc1\n\t"
                     "s_waitcnt vmcnt(0)" : "=&v"(g7) : "v"(bp2) : "memory");
      } while (!((g7[1]==tag) & (g7[3]==tag)) && ++gd < 32768u);
    }
    u32x4 hi0, hi1, lo0, lo1;
    hi0[0]=(q0[0]&0xFFFFu)|(q0[2]<<16); lo0[0]=(q0[0]>>16)|(q0[2]&0xFFFF0000u);
    hi0[1]=(q1[0]&0xFFFFu)|(q1[2]<<16); lo0[1]=(q1[0]>>16)|(q1[2]&0xFFFF0000u);
    hi0[2]=(q2[0]&0xFFFFu)|(q2[2]<<16); lo0[2]=(q2[0]>>16)|(q2[2]&0xFFFF0000u);
    hi0[3]=(q3[0]&0xFFFFu)|(q3[2]<<16); lo0[3]=(q3[0]>>16)|(q3[2]&0xFFFF0000u);
    hi1[0]=(q4[0]&0xFFFFu)|(q4[2]<<16); lo1[0]=(q4[0]>>16)|(q4[2]&0xFFFF0000u);
    hi1[1]=(q5[0]&0xFFFFu)|(q5[2]<<16); lo1[1]=(q5[0]>>16)|(q5[2]&0xFFFF0000u);
    hi1[2]=(q6[0]&0xFFFFu)|(q6[2]<<16); lo1[2]=(q6[0]>>16)|(q6[2]&0xFFFF0000u);
    hi1[3]=(q7[0]&0xFFFFu)|(q7[2]<<16); lo1[3]=(q7[0]>>16)|(q7[2]&0xFFFF0000u);
    const uint32_t base = (uint32_t)(row*512 + ch*32);
    const uint32_t swz  = (uint32_t)((row & 7) << 4);
    *(u32x4*)(smem + dhib + (base ^ swz))        = hi0;
    *(u32x4*)(smem + dhib + ((base + 16) ^ swz)) = hi1;
    *(u32x4*)(smem + dlob + (base ^ swz))        = lo0;
    *(u32x4*)(smem + dlob + ((base + 16) ^ swz)) = lo1;
  };

  float h0keep = 0.f, h1keep = 0.f;
  const float* bb = (const float*)(smem + BIASO);
  const float* S  = (const float*)(smem + SCR);
  const float INV = 1.0f/2048.0f;
  const f32x4 Z = {0.f, 0.f, 0.f, 0.f};
  const int ef   = tid & 15;
  const int sidx = (tid >> 4)*17 + ef;
  const uint32_t pidx = (uint32_t)(cl*4096 + (tid >> 4)*256 + p*16 + ef)*2u;

  half8 a1h[8], a1l[8], a0h[8], a0l[8];

#pragma unroll 1
  for (int t = 0; t < 512; ++t) {
    uint32_t* pb0 = pub + (uint32_t)(t & 1)*65536u;
    uint32_t* pb1 = pub + 131072u + (uint32_t)(t & 1)*65536u;

    LDA(a1h, HB_HI); LDA(a1l, HB_LO);   // h1(t-1) / x0
    LDA(a0h, HA_HI); LDA(a0l, HA_LO);   // h0(t-1) (garbage at t=0, unused)

    // ---- phase A
    f32x4 accP = Z, accQ = Z;
    if (t == 0) {
      if (wv < 3) {
        f32x4 m = CHG(a1h, HIU(1,p,wv), Z);
        f32x4 c = CHG(a1l, HIU(1,p,wv), Z);
        c = CHG(a1h, LOU(1,p,wv), c);
        accP = m + c*INV;
      }
    } else {
      const half8* Ah = (wv == 3) ? a0h : a1h;
      const half8* Al = (wv == 3) ? a0l : a1l;
      f32x4 m = CH(Ah, wPh, Z);
      f32x4 c = CH(Al, wPh, Z);
      c = CH(Ah, wPl, c);
      accP = m + c*INV;
      if (wv < 2) {
        m = CH(a0h, wQh, Z);
        c = CH(a0l, wQh, Z);
        c = CH(a0h, wQl, c);
        accQ = m + c*INV;
      }
    }
    {
      const int slotP = (wv == 0) ? 0 : (wv == 1) ? 1 : (wv == 2) ? 2 : 5;
      SCW(slotP, accP);
      if (wv < 2) SCW(3 + wv, accQ);
    }
    __syncthreads();

    // ---- elementwise layer 0 -> tagged publish
    {
      const float* bA = bb + (t == 0 ? 48 : 0);
      float ir = S[sidx]        + bA[ef];
      float iz = S[288 + sidx]  + bA[16 + ef];
      float ix = S[576 + sidx]  + bA[32 + ef];
      float hr = S[864 + sidx]  + bb[96 + ef];
      float hz = S[1152 + sidx] + bb[112 + ef];
      float hn = S[1440 + sidx] + bb[128 + ef];
      float rg = sigmoidf_(ir + hr);
      float zg = sigmoidf_(iz + hz);
      float ng = tanhf(ix + rg*hn);
      float h  = (1.f - zg)*ng + zg*h0keep;
      h0keep = h;
      _Float16 hh = (_Float16)h;
      _Float16 hl = (_Float16)((h - (float)hh)*2048.f);
      u32x2 pv;
      pv[0] = (uint32_t)__builtin_bit_cast(uint16_t, hh)
            | ((uint32_t)__builtin_bit_cast(uint16_t, hl) << 16);
      pv[1] = (uint32_t)(t*2 + 1);
      st_cc_x2(pb0 + pidx, pv);
    }
    passemble(HA_HI, HA_LO, pb0, (uint32_t)(t*2 + 1));   // full h0n
    __syncthreads();

    // ---- phase B (reload a0 <- h0n; a1 still holds h1(t-1))
    {
      LDA(a0h, HA_HI); LDA(a0l, HA_LO);
      f32x4 accR = Z, accS = Z;
      if (t == 0) {
        if (wv < 3) {
          f32x4 m = CH(a0h, wRh, Z);
          f32x4 c = CH(a0l, wRh, Z);
          c = CHL(a0h, rloofs, c);
          accR = m + c*INV;
        }
      } else {
        const half8* Ah = (wv == 3) ? a1h : a0h;
        const half8* Al = (wv == 3) ? a1l : a0l;
        f32x4 m = CH(Ah, wRh, Z);
        f32x4 c = CH(Al, wRh, Z);
        c = CHL(Ah, rloofs, c);
        accR = m + c*INV;
        if (wv >= 2) {
          m = CH(a1h, wSh, Z);
          c = CH(a1l, wSh, Z);
          c = CHL(a1h, sloofs, c);
          accS = m + c*INV;
        }
      }
      const int slotR = (wv == 0) ? 0 : (wv == 1) ? 1 : (wv == 2) ? 2 : 4;
      SCW(slotR, accR);
      if (wv >= 2) SCW((wv == 2) ? 3 : 5, accS);
    }
    __syncthreads();

    // ---- elementwise layer 1 -> tagged publish
    {
      float ir = S[sidx]        + bb[144 + ef];
      float iz = S[288 + sidx]  + bb[160 + ef];
      float ix = S[576 + sidx]  + bb[176 + ef];
      float hr = S[864 + sidx]  + bb[192 + ef];
      float hz = S[1152 + sidx] + bb[208 + ef];
      float hn = S[1440 + sidx] + bb[224 + ef];
      float rg = sigmoidf_(ir + hr);
      float zg = sigmoidf_(iz + hz);
      float ng = tanhf(ix + rg*hn);
      float h  = (1.f - zg)*ng + zg*h1keep;
      h1keep = h;
      _Float16 hh = (_Float16)h;
      _Float16 hl = (_Float16)((h - (float)hh)*2048.f);
      u32x2 pv;
      pv[0] = (uint32_t)__builtin_bit_cast(uint16_t, hh)
            | ((uint32_t)__builtin_bit_cast(uint16_t, hl) << 16);
      pv[1] = (uint32_t)(t*2 + 2);
      st_cc_x2(pb1 + pidx, pv);
    }
    passemble(HB_HI, HB_LO, pb1, (uint32_t)(t*2 + 2));   // full h1n
    __syncthreads();

    // ---- heads (wave 3): note/dur/gap from h1n (hi part; one-shot error ~5e-4)
    if (wv == 3) {
      half8 fh[8];
      LDA(fh, HB_HI);
      f32x4 hc = CHL(fh, WLDS + 65536u, Z);
      const int col = lane & 15;
      const int jgl = p*16 + col;
      const float bo = bb[240 + col];
#pragma unroll
      for (int r = 0; r < 4; ++r) {
        const int brow = cl*16 + (lane >> 4)*4 + r;
        const float v = hc[r] + bo;
        size_t o;
        if (jgl < 128)      o = ((size_t)brow*512 + (size_t)t)*128 + (size_t)jgl;
        else if (jgl < 192) o = 8388608u  + ((size_t)brow*512 + (size_t)t)*64 + (size_t)(jgl - 128);
        else                o = 12582912u + ((size_t)brow*512 + (size_t)t)*64 + (size_t)(jgl - 192);
        out[o] = v;
      }
    }
  }
}

// ---------------------------------------------------------------------------
extern "C" void kernel_launch(void* const* d_in, const int* in_sizes, int n_in,
                              void* d_out, int out_size, void* d_ws, size_t ws_size,
                              hipStream_t stream) {
  (void)in_sizes; (void)n_in; (void)out_size;
  const float* x0   = (const float*)d_in[2];
  const float* Wih0 = (const float*)d_in[3];
  const float* Whh0 = (const float*)d_in[4];
  const float* bih0 = (const float*)d_in[5];
  const float* bhh0 = (const float*)d_in[6];
  const float* Wih1 = (const float*)d_in[7];
  const float* Whh1 = (const float*)d_in[8];
  const float* bih1 = (const float*)d_in[9];
  const float* bhh1 = (const float*)d_in[10];
  const float* Wn   = (const float*)d_in[11];
  const float* bn   = (const float*)d_in[12];
  const float* Wd   = (const float*)d_in[13];
  const float* bd   = (const float*)d_in[14];
  const float* Wg   = (const float*)d_in[15];
  const float* bg   = (const float*)d_in[16];

  if (ws_size < WS_NEEDED) return;  // fail loudly (poisoned output) rather than corrupt

  char* ws = (char*)d_ws;
  uint32_t* pub = (uint32_t*)(ws + PUB_OFF);
  float*    bp  = (float*)(ws + BP_OFF);
  uint16_t* BW  = (uint16_t*)(ws + BLOB_OFF);

  gru_init1<<<768, 256, 0, stream>>>(Wih0, Wn, Wd, Wg, bn, bd, bg, bih0, BW, bp);
  gru_init2<<<992, 256, 0, stream>>>(Wih0, Whh0, Wih1, Whh1, Wn, Wd, Wg, pub, BW);
  gru_main <<<128, 256, LDS_TOTAL, stream>>>(x0, bih0, bhh0, bih1, bhh1, bn, bd, bg, bp,
                                             BW, pub, (float*)d_out);
}

// Round 6
// 2739.330 us; speedup vs baseline: 1.8056x; 1.8056x over previous
//
#include <hip/hip_runtime.h>
#include <stdint.h>

// ============================================================================
// 2-layer GRU decoder, B=128, T=512, H=256, heads 128/64/64 (concat=256).
// Persistent latency design + SPLIT-F16 precision (effectively fp32 matmuls):
//   A*W ~= Ah*Wh + (Al_s*Wh + Ah*Wl_s)/2048, lo-parts pre-scaled by 2^11.
// Sync (round-3 validated): per-block monotonic flags + pub data, ALL via
//   system-scope (sc0 sc1) ops at the LLC. Re-zeroed each launch by init2.
//   NOTE (round-5 lesson): sc0-only is CU/workgroup scope on gfx950 — NOT
//   sufficient for cross-CU visibility. sc0 sc1 (system) is the proven pair.
// Latency overlap (new, inspected): gh1(t) computed under exchange-1 poll,
//   gh0(t+1) under exchange-2 poll, head(t-1) during phase A on wave 3 —
//   only gi0 -> L0 -> ex1 -> gi1 -> L1 -> ex2 remains on the serial chain.
// ============================================================================

typedef __attribute__((ext_vector_type(8))) _Float16 half8;
typedef __attribute__((ext_vector_type(4))) float f32x4;
typedef __attribute__((ext_vector_type(4))) unsigned int u32x4;

// blob fragment-unit (16B) section bases: b=0 W', 1 Wih0, 2 Whh0, 3 Wih1, 4 Whh1
#define HIU(b,p,g)  ((unsigned)((b)*24576u + ((p)*3u+(g))*512u))
#define LOU(b,p,g)  ((unsigned)(122880u + (b)*24576u + ((p)*3u+(g))*512u))
#define HEADU(p)    ((unsigned)(245760u + (p)*512u))
#define NUNITS      253952u

// workspace offsets (bytes)
#define FLAGS_OFF 0u            // flag of block (cl,p) at u32 index (cl*16+p)*16
#define PUB0_OFF  16384u        // 32768 u32 (hi|lo<<16)
#define PUB1_OFF  147456u
#define BP_OFF    278528u
#define BLOB_OFF  281600u
#define WS_NEEDED (BLOB_OFF + NUNITS*16u)

// LDS offsets (bytes)
#define HA_HI 0u
#define HA_LO 8192u
#define HB_HI 16384u
#define HB_LO 24576u
#define SCR   32768u        // 9 slots * 288 fp32 (17-stride pad) = 10368B
#define BIASO 43136u        // 256 floats
#define WLDS  44160u        // wv1..3: h1lo+h0lo (16KB each); head hi at +49152
#define LDS_TOTAL (44160u + 57344u)   // 101504 B

__device__ __forceinline__ uint16_t f2h_bits(float x) {
  _Float16 h = (_Float16)x;
  return __builtin_bit_cast(uint16_t, h);
}
__device__ __forceinline__ float sigmoidf_(float x) { return 1.f / (1.f + __expf(-x)); }

// system-scope (LLC) coherent store — validated round 3
__device__ __forceinline__ void st_cc_d(uint32_t* p, uint32_t v) {
  asm volatile("global_store_dword %0, %1, off sc0 sc1" :: "v"(p), "v"(v) : "memory");
}

// ---------------------------------------------------------------------------
// init1: W' = Wih0 @ Wcat written DIRECTLY as split-f16 blob (b=0 sections);
//        b' = bih0 + Wih0 . bcat -> bp.   (validated round 4)
// ---------------------------------------------------------------------------
__global__ void gru_init1(const float* __restrict__ Wih0, const float* __restrict__ Wn,
                          const float* __restrict__ Wd, const float* __restrict__ Wg,
                          const float* __restrict__ bn, const float* __restrict__ bd,
                          const float* __restrict__ bg, const float* __restrict__ bih0,
                          uint16_t* __restrict__ BW, float* __restrict__ bp)
{
  const int i = blockIdx.x;   // 0..767  (gate-major row of W')
  const int j = threadIdx.x;  // 0..255  (column)
  float acc = 0.f;
  for (int k = 0; k < 256; ++k) {
    float w = Wih0[i*256 + k];
    float c = (k < 128) ? Wn[k*256 + j] : (k < 192) ? Wd[(k-128)*256 + j] : Wg[(k-192)*256 + j];
    acc += w * c;
  }
  const uint32_t g = (uint32_t)i >> 8, p = ((uint32_t)i & 255u) >> 4, r = (uint32_t)i & 15u;
  const uint32_t kt = (uint32_t)j >> 5, c4 = ((uint32_t)j >> 3) & 3u, e = (uint32_t)j & 7u;
  const uint32_t base = ((p*3u + g)*512u + kt*64u + c4*16u + r)*8u + e;
  _Float16 hi = (_Float16)acc;
  BW[base] = __builtin_bit_cast(uint16_t, hi);
  BW[122880u*8u + base] = f2h_bits((acc - (float)hi) * 2048.f);
  if (j == 0) {
    float bb = bih0[i];
    for (int k = 0; k < 256; ++k) {
      float bc = (k < 128) ? bn[k] : (k < 192) ? bd[k-128] : bg[k-192];
      bb += Wih0[i*256 + k] * bc;
    }
    bp[i] = bb;
  }
}

// ---------------------------------------------------------------------------
// init2: split-f16 blobs for b=1..4 + head; b=0-range threads zero the flags
// (system-scope stores -> visible to gru_main's sc0 sc1 loads; replay-safe).
// ---------------------------------------------------------------------------
__global__ void gru_init2(const float* __restrict__ Wih0, const float* __restrict__ Whh0,
                          const float* __restrict__ Wih1, const float* __restrict__ Whh1,
                          const float* __restrict__ Wn, const float* __restrict__ Wd,
                          const float* __restrict__ Wg,
                          uint32_t* __restrict__ flags, uint16_t* __restrict__ BW)
{
  const uint32_t u = blockIdx.x*256u + threadIdx.x;   // 0..253951
  const bool isB0 = (u < 24576u) || (u >= 122880u && u < 147456u);
  if (isB0) {
    const uint32_t zi = (u < 24576u) ? u : (u - 122880u + 24576u);  // 0..49151
    if (zi < 2048u) st_cc_d(flags + zi, 0u);
    return;
  }
  bool lo = false;
  const float* s;
  if (u < 245760u) {
    uint32_t v = u;
    if (v >= 122880u) { v -= 122880u; lo = true; }
    uint32_t b = v/24576u, rem = v%24576u;          // b in 1..4 here
    uint32_t p = rem/1536u, r2 = rem%1536u;
    uint32_t g = r2/512u,  r3 = r2%512u;
    uint32_t kt = r3>>6,   l = r3&63u;
    const float* W = (b==1)?Wih0:(b==2)?Whh0:(b==3)?Wih1:Whh1;
    s = W + (size_t)(g*256u + p*16u + (l&15u))*256u + kt*32u + (l>>4)*8u;
  } else {
    uint32_t rem = u - 245760u;
    uint32_t p = rem/512u, r3 = rem%512u;
    uint32_t kt = r3>>6,   l = r3&63u;
    uint32_t row = p*16u + (l&15u), k0 = kt*32u + (l>>4)*8u;
    s = (row < 128u) ? (Wn + (size_t)row*256u + k0)
      : (row < 192u) ? (Wd + (size_t)(row-128u)*256u + k0)
      :                (Wg + (size_t)(row-192u)*256u + k0);
  }
  u32x4 vv;
#pragma unroll
  for (int i = 0; i < 4; ++i) {
    float w0 = s[2*i], w1 = s[2*i+1];
    uint16_t b0, b1;
    if (!lo) { b0 = f2h_bits(w0); b1 = f2h_bits(w1); }
    else {
      float r0 = w0 - (float)((_Float16)w0);
      float r1 = w1 - (float)((_Float16)w1);
      b0 = f2h_bits(r0 * 2048.f); b1 = f2h_bits(r1 * 2048.f);
    }
    vv[i] = (uint32_t)b0 | ((uint32_t)b1 << 16);
  }
  *(u32x4*)(BW + (size_t)u * 8u) = vv;
}

// ---------------------------------------------------------------------------
// main persistent kernel: 128 blocks x 256 threads, 512 steps.
// ---------------------------------------------------------------------------
__launch_bounds__(256, 1)
__global__ void gru_main(const float* __restrict__ x0in,
                         const float* __restrict__ bih0, const float* __restrict__ bhh0,
                         const float* __restrict__ bih1, const float* __restrict__ bhh1,
                         const float* __restrict__ bn, const float* __restrict__ bd,
                         const float* __restrict__ bg, const float* __restrict__ bp,
                         const uint16_t* __restrict__ BW,
                         uint32_t* __restrict__ flags,
                         uint32_t* __restrict__ pub0, uint32_t* __restrict__ pub1,
                         float* __restrict__ out)
{
  extern __shared__ char smem[];
  const int tid  = threadIdx.x;
  const int lane = tid & 63;
  const int wv   = tid >> 6;
  const int cl   = blockIdx.x & 7;
  const int p    = blockIdx.x >> 3;

  // ---- biases -> LDS: [0)b' [48)bih0 [96)bhh0 [144)bih1 [192)bhh1 [240)bhead
  if (tid < 48) {
    const int gi = (tid >> 4)*256 + p*16 + (tid & 15);
    float* bbw = (float*)(smem + BIASO);
    bbw[tid]       = bp[gi];
    bbw[48 + tid]  = bih0[gi];
    bbw[96 + tid]  = bhh0[gi];
    bbw[144 + tid] = bih1[gi];
    bbw[192 + tid] = bhh1[gi];
  }
  if (tid < 16) {
    const int jg = p*16 + tid;
    float v = (jg < 128) ? bn[jg] : (jg < 192) ? bd[jg-128] : bg[jg-192];
    ((float*)(smem + BIASO))[240 + tid] = v;
  }
  // ---- zero gh0/gh1 scratch slots (3..8) for t=0 semantics ----
  {
    float* S0 = (float*)(smem + SCR);
    const int sidx0 = (tid >> 4)*17 + (tid & 15);
#pragma unroll
    for (int s = 3; s < 9; ++s) S0[s*288 + sidx0] = 0.f;
  }
  // ---- x0 -> HB hi/lo (split f16, XOR-swizzled; round-3 validated layout) ----
  {
    const int row = tid >> 4, ch = tid & 15;
    const float* sp = x0in + (size_t)(cl*16 + row)*256 + ch*16;
    const uint32_t base = (uint32_t)(row*512 + ch*32);
    const uint32_t swz  = (uint32_t)((row & 7) << 4);
#pragma unroll
    for (int half = 0; half < 2; ++half) {
      u32x4 vh, vl;
#pragma unroll
      for (int i = 0; i < 4; ++i) {
        float w0 = sp[half*8 + 2*i], w1 = sp[half*8 + 2*i + 1];
        _Float16 h0 = (_Float16)w0, h1 = (_Float16)w1;
        _Float16 l0 = (_Float16)((w0 - (float)h0)*2048.f);
        _Float16 l1 = (_Float16)((w1 - (float)h1)*2048.f);
        vh[i] = (uint32_t)__builtin_bit_cast(uint16_t,h0) | ((uint32_t)__builtin_bit_cast(uint16_t,h1) << 16);
        vl[i] = (uint32_t)__builtin_bit_cast(uint16_t,l0) | ((uint32_t)__builtin_bit_cast(uint16_t,l1) << 16);
      }
      *(u32x4*)(smem + HB_HI + ((base + half*16) ^ swz)) = vh;
      *(u32x4*)(smem + HB_LO + ((base + half*16) ^ swz)) = vl;
    }
  }

  // ---- weight fragments -> registers
  // wv0-2: W' gate wv (hi+lo), Wih1 gate wv (hi+lo) in regs.
  // wv1-3: Whh1 gate wv-1 (hi), Whh0 gate wv-1 (hi) in regs; lo-sets in LDS.
  // wv3: head weights (hi) in LDS.
  half8 wGIh[8], wGIl[8], wI1h[8], wI1l[8], wH1h[8], wH0h[8];
  if (wv < 3) {
#pragma unroll
    for (int kt = 0; kt < 8; ++kt) {
      wGIh[kt] = *(const half8*)(BW + (size_t)(HIU(0,p,wv) + kt*64 + lane)*8);
      wGIl[kt] = *(const half8*)(BW + (size_t)(LOU(0,p,wv) + kt*64 + lane)*8);
      wI1h[kt] = *(const half8*)(BW + (size_t)(HIU(3,p,wv) + kt*64 + lane)*8);
      wI1l[kt] = *(const half8*)(BW + (size_t)(LOU(3,p,wv) + kt*64 + lane)*8);
    }
  }
  const uint32_t h1lo_ofs = WLDS + (uint32_t)(wv-1)*16384u;   // valid for wv>=1
  const uint32_t h0lo_ofs = h1lo_ofs + 8192u;
  if (wv >= 1) {
    const int g = wv - 1;
#pragma unroll
    for (int kt = 0; kt < 8; ++kt) {
      wH1h[kt] = *(const half8*)(BW + (size_t)(HIU(4,p,g) + kt*64 + lane)*8);
      wH0h[kt] = *(const half8*)(BW + (size_t)(HIU(2,p,g) + kt*64 + lane)*8);
      *(u32x4*)(smem + h1lo_ofs + (uint32_t)((kt*64 + lane)*16)) =
          *(const u32x4*)(BW + (size_t)(LOU(4,p,g) + kt*64 + lane)*8);
      *(u32x4*)(smem + h0lo_ofs + (uint32_t)((kt*64 + lane)*16)) =
          *(const u32x4*)(BW + (size_t)(LOU(2,p,g) + kt*64 + lane)*8);
    }
  }
  if (wv == 3) {
#pragma unroll
    for (int kt = 0; kt < 8; ++kt)
      *(u32x4*)(smem + WLDS + 49152u + (uint32_t)((kt*64 + lane)*16)) =
          *(const u32x4*)(BW + (size_t)(HEADU(p) + kt*64 + lane)*8);
  }
  __syncthreads();

  const int arow = lane & 15;
  const uint32_t abase = (uint32_t)(arow*512 + ((lane >> 4) << 4));
  const uint32_t aswz  = (uint32_t)((arow & 7) << 4);

  auto LDA = [&](half8* dst, uint32_t buf) {
#pragma unroll
    for (int kt = 0; kt < 8; ++kt)
      dst[kt] = *(const half8*)(smem + buf + ((abase + (uint32_t)(kt*64)) ^ aswz));
  };
  auto CH = [&](const half8* A, const half8* W, f32x4 acc) -> f32x4 {
#pragma unroll
    for (int kt = 0; kt < 8; ++kt)
      acc = __builtin_amdgcn_mfma_f32_16x16x32_f16(A[kt], W[kt], acc, 0, 0, 0);
    return acc;
  };
  auto CHL = [&](const half8* A, uint32_t wofs, f32x4 acc) -> f32x4 {
#pragma unroll
    for (int kt = 0; kt < 8; ++kt) {
      half8 w = *(const half8*)(smem + wofs + (uint32_t)((kt*64 + lane)*16));
      acc = __builtin_amdgcn_mfma_f32_16x16x32_f16(A[kt], w, acc, 0, 0, 0);
    }
    return acc;
  };
  auto CHG = [&](const half8* A, unsigned ubase, f32x4 acc) -> f32x4 {
#pragma unroll
    for (int kt = 0; kt < 8; ++kt) {
      half8 w = *(const half8*)(BW + (size_t)(ubase + kt*64 + lane)*8);
      acc = __builtin_amdgcn_mfma_f32_16x16x32_f16(A[kt], w, acc, 0, 0, 0);
    }
    return acc;
  };
  auto SCW = [&](int slot, f32x4 a) {   // C layout: col=lane&15, row=(lane>>4)*4+r
    float* sc = (float*)(smem + SCR) + slot*288 + (lane >> 4)*68 + (lane & 15);
    sc[0] = a[0]; sc[17] = a[1]; sc[34] = a[2]; sc[51] = a[3];
  };
  auto pollf = [&](uint32_t fval) {   // wave-0 only; 16 flags, system scope
    const uint32_t* fp = flags + (cl*16 + (lane & 15))*16;
    uint32_t gd = 0;
    for (;;) {
      uint32_t fv;
      asm volatile("global_load_dword %0, %1, off sc0 sc1\n\ts_waitcnt vmcnt(0)"
                   : "=&v"(fv) : "v"(fp) : "memory");
      if (__all((int)(fv >= fval)) || ++gd > 65536u) break;   // bail, don't hang
    }
  };
  auto assemble = [&](uint32_t dhib, uint32_t dlob, const uint32_t* buf) {
    const int row = tid >> 4, ch = tid & 15;
    const uint32_t* bp2 = buf + (uint32_t)(cl*4096 + row*256 + ch*16);
    u32x4 q0, q1, q2, q3;
    asm volatile(
      "global_load_dwordx4 %0, %4, off sc0 sc1\n\t"
      "global_load_dwordx4 %1, %4, off offset:16 sc0 sc1\n\t"
      "global_load_dwordx4 %2, %4, off offset:32 sc0 sc1\n\t"
      "global_load_dwordx4 %3, %4, off offset:48 sc0 sc1\n\t"
      "s_waitcnt vmcnt(0)"
      : "=&v"(q0), "=&v"(q1), "=&v"(q2), "=&v"(q3) : "v"(bp2) : "memory");
    u32x4 hi0, hi1, lo0, lo1;
    hi0[0]=(q0[0]&0xFFFFu)|(q0[1]<<16); lo0[0]=(q0[0]>>16)|(q0[1]&0xFFFF0000u);
    hi0[1]=(q0[2]&0xFFFFu)|(q0[3]<<16); lo0[1]=(q0[2]>>16)|(q0[3]&0xFFFF0000u);
    hi0[2]=(q1[0]&0xFFFFu)|(q1[1]<<16); lo0[2]=(q1[0]>>16)|(q1[1]&0xFFFF0000u);
    hi0[3]=(q1[2]&0xFFFFu)|(q1[3]<<16); lo0[3]=(q1[2]>>16)|(q1[3]&0xFFFF0000u);
    hi1[0]=(q2[0]&0xFFFFu)|(q2[1]<<16); lo1[0]=(q2[0]>>16)|(q2[1]&0xFFFF0000u);
    hi1[1]=(q2[2]&0xFFFFu)|(q2[3]<<16); lo1[1]=(q2[2]>>16)|(q2[3]&0xFFFF0000u);
    hi1[2]=(q3[0]&0xFFFFu)|(q3[1]<<16); lo1[2]=(q3[0]>>16)|(q3[1]&0xFFFF0000u);
    hi1[3]=(q3[2]&0xFFFFu)|(q3[3]<<16); lo1[3]=(q3[2]>>16)|(q3[3]&0xFFFF0000u);
    const uint32_t base = (uint32_t)(row*512 + ch*32);
    const uint32_t swz  = (uint32_t)((row & 7) << 4);
    *(u32x4*)(smem + dhib + (base ^ swz))        = hi0;
    *(u32x4*)(smem + dhib + ((base + 16) ^ swz)) = hi1;
    *(u32x4*)(smem + dlob + (base ^ swz))        = lo0;
    *(u32x4*)(smem + dlob + ((base + 16) ^ swz)) = lo1;
  };

  float h0keep = 0.f, h1keep = 0.f;
  const float* bb = (const float*)(smem + BIASO);
  const float* S  = (const float*)(smem + SCR);
  const float INV = 1.0f/2048.0f;
  const f32x4 Z = {0.f, 0.f, 0.f, 0.f};
  const int ef   = tid & 15;
  const int sidx = (tid >> 4)*17 + ef;
  const uint32_t pidx = (uint32_t)(cl*4096 + (tid >> 4)*256 + p*16 + ef);
  uint32_t* myflag = flags + (cl*16 + p)*16;

  half8 a1h[8], a1l[8], a0h[8], a0l[8];

  auto head_out = [&](int tstep) {   // uses a1h (= h1n(tstep) from HB)
    f32x4 hc = CHL(a1h, WLDS + 49152u, Z);
    const int col = lane & 15;
    const int jgl = p*16 + col;
    const float bo = bb[240 + col];
#pragma unroll
    for (int r = 0; r < 4; ++r) {
      const int brow = cl*16 + (lane >> 4)*4 + r;
      const float v = hc[r] + bo;
      size_t o;
      if (jgl < 128)      o = ((size_t)brow*512 + (size_t)tstep)*128 + (size_t)jgl;
      else if (jgl < 192) o = 8388608u  + ((size_t)brow*512 + (size_t)tstep)*64 + (size_t)(jgl - 128);
      else                o = 12582912u + ((size_t)brow*512 + (size_t)tstep)*64 + (size_t)(jgl - 192);
      out[o] = v;
    }
  };

#pragma unroll 1
  for (int t = 0; t < 512; ++t) {
    LDA(a1h, HB_HI); LDA(a1l, HB_LO);   // h1(t-1) / x0

    // ---- phase A: gi0 (wv0-2); head(t-1) on wv3
    if (t == 0) {
      if (wv < 3) {
        f32x4 m = CHG(a1h, HIU(1,p,wv), Z);
        f32x4 c = CHG(a1l, HIU(1,p,wv), Z);
        c = CHG(a1h, LOU(1,p,wv), c);
        SCW(wv, m + c*INV);
      }
    } else {
      if (wv < 3) {
        f32x4 m = CH(a1h, wGIh, Z);
        f32x4 c = CH(a1l, wGIh, Z);
        c = CH(a1h, wGIl, c);
        SCW(wv, m + c*INV);
      } else {
        head_out(t - 1);
      }
    }
    __syncthreads();

    // ---- elementwise layer 0 -> publish h0n  (gh0(t) from slots 3-5)
    {
      const float* bA = bb + (t == 0 ? 48 : 0);
      float ir = S[sidx]        + bA[ef];
      float iz = S[288 + sidx]  + bA[16 + ef];
      float ix = S[576 + sidx]  + bA[32 + ef];
      float hr = S[864 + sidx]  + bb[96 + ef];
      float hz = S[1152 + sidx] + bb[112 + ef];
      float hn = S[1440 + sidx] + bb[128 + ef];
      float rg = sigmoidf_(ir + hr);
      float zg = sigmoidf_(iz + hz);
      float ng = tanhf(ix + rg*hn);
      float h  = (1.f - zg)*ng + zg*h0keep;
      h0keep = h;
      _Float16 hh = (_Float16)h;
      _Float16 hl = (_Float16)((h - (float)hh)*2048.f);
      st_cc_d(pub0 + pidx, (uint32_t)__builtin_bit_cast(uint16_t, hh)
                         | ((uint32_t)__builtin_bit_cast(uint16_t, hl) << 16));
    }
    asm volatile("s_waitcnt vmcnt(0)" ::: "memory");
    __syncthreads();
    if (tid == 0) st_cc_d(myflag, (uint32_t)(t*2 + 1));
    // exchange-1 window: gh1(t) = Whh1 . h1(t-1) on wv1-3; wv0 polls
    if (t > 0 && wv >= 1) {
      f32x4 m = CH(a1h, wH1h, Z);
      f32x4 c = CH(a1l, wH1h, Z);
      c = CHL(a1h, h1lo_ofs, c);
      SCW(5 + wv, m + c*INV);     // slots 6,7,8 (gates r,z,n)
    }
    if (wv == 0) pollf((uint32_t)(t*2 + 1));
    __syncthreads();
    assemble(HA_HI, HA_LO, pub0);   // full h0n(t)
    __syncthreads();

    // ---- phase B: gi1 (wv0-2)
    LDA(a0h, HA_HI); LDA(a0l, HA_LO);
    if (wv < 3) {
      f32x4 m = CH(a0h, wI1h, Z);
      f32x4 c = CH(a0l, wI1h, Z);
      c = CH(a0h, wI1l, c);
      SCW(wv, m + c*INV);
    }
    __syncthreads();

    // ---- elementwise layer 1 -> publish h1n  (gh1(t) from slots 6-8)
    {
      float ir = S[sidx]        + bb[144 + ef];
      float iz = S[288 + sidx]  + bb[160 + ef];
      float ix = S[576 + sidx]  + bb[176 + ef];
      float hr = S[1728 + sidx] + bb[192 + ef];
      float hz = S[2016 + sidx] + bb[208 + ef];
      float hn = S[2304 + sidx] + bb[224 + ef];
      float rg = sigmoidf_(ir + hr);
      float zg = sigmoidf_(iz + hz);
      float ng = tanhf(ix + rg*hn);
      float h  = (1.f - zg)*ng + zg*h1keep;
      h1keep = h;
      _Float16 hh = (_Float16)h;
      _Float16 hl = (_Float16)((h - (float)hh)*2048.f);
      st_cc_d(pub1 + pidx, (uint32_t)__builtin_bit_cast(uint16_t, hh)
                         | ((uint32_t)__builtin_bit_cast(uint16_t, hl) << 16));
    }
    asm volatile("s_waitcnt vmcnt(0)" ::: "memory");
    __syncthreads();
    if (tid == 0) st_cc_d(myflag, (uint32_t)(t*2 + 2));
    // exchange-2 window: gh0(t+1) = Whh0 . h0n(t) on wv1-3; wv0 polls
    if (wv >= 1) {
      f32x4 m = CH(a0h, wH0h, Z);
      f32x4 c = CH(a0l, wH0h, Z);
      c = CHL(a0h, h0lo_ofs, c);
      SCW(2 + wv, m + c*INV);     // slots 3,4,5 (gates r,z,n)
    }
    if (wv == 0) pollf((uint32_t)(t*2 + 2));
    __syncthreads();
    assemble(HB_HI, HB_LO, pub1);   // full h1n(t)
    __syncthreads();
  }

  // epilogue: head for t=511
  if (wv == 3) {
    LDA(a1h, HB_HI);
    head_out(511);
  }
}

// ---------------------------------------------------------------------------
extern "C" void kernel_launch(void* const* d_in, const int* in_sizes, int n_in,
                              void* d_out, int out_size, void* d_ws, size_t ws_size,
                              hipStream_t stream) {
  (void)in_sizes; (void)n_in; (void)out_size;
  const float* x0   = (const float*)d_in[2];
  const float* Wih0 = (const float*)d_in[3];
  const float* Whh0 = (const float*)d_in[4];
  const float* bih0 = (const float*)d_in[5];
  const float* bhh0 = (const float*)d_in[6];
  const float* Wih1 = (const float*)d_in[7];
  const float* Whh1 = (const float*)d_in[8];
  const float* bih1 = (const float*)d_in[9];
  const float* bhh1 = (const float*)d_in[10];
  const float* Wn   = (const float*)d_in[11];
  const float* bn   = (const float*)d_in[12];
  const float* Wd   = (const float*)d_in[13];
  const float* bd   = (const float*)d_in[14];
  const float* Wg   = (const float*)d_in[15];
  const float* bg   = (const float*)d_in[16];

  if (ws_size < WS_NEEDED) return;  // fail loudly (poisoned output) rather than corrupt

  char* ws = (char*)d_ws;
  uint32_t* flags = (uint32_t*)(ws + FLAGS_OFF);
  uint32_t* pub0  = (uint32_t*)(ws + PUB0_OFF);
  uint32_t* pub1  = (uint32_t*)(ws + PUB1_OFF);
  float*    bp    = (float*)(ws + BP_OFF);
  uint16_t* BW    = (uint16_t*)(ws + BLOB_OFF);

  gru_init1<<<768, 256, 0, stream>>>(Wih0, Wn, Wd, Wg, bn, bd, bg, bih0, BW, bp);
  gru_init2<<<992, 256, 0, stream>>>(Wih0, Whh0, Wih1, Whh1, Wn, Wd, Wg, flags, BW);
  gru_main <<<128, 256, LDS_TOTAL, stream>>>(x0, bih0, bhh0, bih1, bhh1, bn, bd, bg, bp,
                                             BW, flags, pub0, pub1, (float*)d_out);
}